// Round 9
// baseline (2695.775 us; speedup 1.0000x reference)
//
#include <hip/hip_runtime.h>
#include <stdint.h>

// B=32, T=128, DIN=DOUT=1024. Input dtypes detected at runtime (bf16 vs fp32).
typedef unsigned short u16;
typedef unsigned long long u64;
typedef __attribute__((ext_vector_type(8))) short short8;   // 8 x bf16 MFMA operand
typedef __attribute__((ext_vector_type(4))) float f32x4;    // MFMA accumulator
typedef __attribute__((ext_vector_type(4))) int i32x4;

#define NBLK 64

// ---- workspace layout (bytes) ----
#define FLAGA_OFF  0                          // 64 per-block epoch flags x 64 B
#define FLG_OFF    4096                       // 13 dtype flags
#define H64_OFF    8192                       // h bf16 as u64[32][256]: 64 KB (zeroed)
#define ZERO_BYTES (H64_OFF + 65536)
#define RH64_OFF   ZERO_BYTES                 // r*h bf16 u64[32][256] (write-before-read)
#define BS_OFF     (RH64_OFF + 65536)         // bias sums fp32: 3*1024*4
#define XB_OFF     (1<<20)                    // x bf16: 8 MB
#define WB_OFF     (9<<20)                    // 6 weight mats bf16: 12 MB
#define WS_FULL    (21u<<20)

__device__ __forceinline__ float bf2f(u16 v) {
    unsigned u = ((unsigned)v) << 16;
    return __builtin_bit_cast(float, u);
}
__device__ __forceinline__ u16 f2bf(float f) {
    unsigned u = __builtin_bit_cast(unsigned, f);
    unsigned r = 0x7fffu + ((u >> 16) & 1u);   // RNE
    return (u16)((u + r) >> 16);
}
__device__ __forceinline__ float sigm(float x) { return 1.0f / (1.0f + __expf(-x)); }

__device__ __forceinline__ short8 cvt8f(const float* f) {
    short8 r;
#pragma unroll
    for (int j = 0; j < 8; j++) r[j] = (short)f2bf(f[j]);
    return r;
}
__device__ __forceinline__ short8 cvt8any(const void* src, long ei, unsigned isbf) {
    if (isbf) return *(const short8*)((const u16*)src + ei);
    return cvt8f((const float*)src + ei);
}

__device__ __forceinline__ unsigned afload(const unsigned* p) {
    return __hip_atomic_load(p, __ATOMIC_RELAXED, __HIP_MEMORY_SCOPE_AGENT);
}

// ---- batched coherent fragment load: 8x dwordx4 sc1 in flight, ONE waitcnt ----
// __hip_atomic_load compiles to the same global_load ... sc1, but LLVM will not
// keep multiple atomic loads in flight (rounds 6-8: 8 serial L3 round trips,
// VGPR_Count 40). This asm block issues all 8 then waits once.
__device__ __forceinline__ void ld8_coh(const u64* b0, const u64* b1, short8* f) {
    i32x4 g0, g1, g2, g3, g4, g5, g6, g7;
    asm volatile(
        "global_load_dwordx4 %0, %[p0], off sc1\n\t"
        "global_load_dwordx4 %1, %[p0], off offset:64 sc1\n\t"
        "global_load_dwordx4 %2, %[p0], off offset:128 sc1\n\t"
        "global_load_dwordx4 %3, %[p0], off offset:192 sc1\n\t"
        "global_load_dwordx4 %4, %[p1], off sc1\n\t"
        "global_load_dwordx4 %5, %[p1], off offset:64 sc1\n\t"
        "global_load_dwordx4 %6, %[p1], off offset:128 sc1\n\t"
        "global_load_dwordx4 %7, %[p1], off offset:192 sc1\n\t"
        "s_waitcnt vmcnt(0)"
        : "=&v"(g0), "=&v"(g1), "=&v"(g2), "=&v"(g3),
          "=&v"(g4), "=&v"(g5), "=&v"(g6), "=&v"(g7)
        : [p0]"v"(b0), [p1]"v"(b1)
        : "memory");
    f[0] = __builtin_bit_cast(short8, g0); f[1] = __builtin_bit_cast(short8, g1);
    f[2] = __builtin_bit_cast(short8, g2); f[3] = __builtin_bit_cast(short8, g3);
    f[4] = __builtin_bit_cast(short8, g4); f[5] = __builtin_bit_cast(short8, g5);
    f[6] = __builtin_bit_cast(short8, g6); f[7] = __builtin_bit_cast(short8, g7);
}

// ---- store/gather grid barrier (64 blocks): no RMW, no fences ----
__device__ __forceinline__ void gbar_arrive(unsigned* fl, unsigned e, int blk) {
    __syncthreads();                 // vmcnt drain: all publish stores at L3
    if (threadIdx.x == 0)
        __hip_atomic_store(&fl[blk * 16], e + 1u,
                           __ATOMIC_RELAXED, __HIP_MEMORY_SCOPE_AGENT);
}
__device__ __forceinline__ void gbar_wait(unsigned* fl, unsigned e) {
    if (threadIdx.x < 64) {
        const unsigned tgt = e + 1u;
        while (!__all(afload(&fl[threadIdx.x * 16]) >= tgt))
            __builtin_amdgcn_s_sleep(1);
    }
    __syncthreads();
}

struct Ptrs { const void* p[13]; };

// dtype detector (proven in rounds 3-8).
__global__ __launch_bounds__(256) void detect_k(Ptrs ps, unsigned* flags) {
    const u16* a = (const u16*)ps.p[blockIdx.x];
    __shared__ int tot;
    if (threadIdx.x == 0) tot = 0;
    __syncthreads();
    int cnt = 0;
    for (int i = threadIdx.x; i < 1024; i += 256) {
        unsigned u = a[i];
        unsigned e = (u >> 7) & 0xFF;
        cnt += (e == 0 || (e >= 100 && e <= 140)) ? 1 : 0;
    }
    atomicAdd(&tot, cnt);
    __syncthreads();
    if (threadIdx.x == 0) flags[blockIdx.x] = (tot >= 920) ? 1u : 0u;
}

struct SPtrs { const void* x; const void* W[6]; const void* b[6]; };
// W order: Wz,Uz,Wr,Ur,Wh,Uh (flags 1,3,5,7,9,11); b pairs (bz,cz),(br,cr),(bh,ch).

__global__ __launch_bounds__(256) void stage_k(SPtrs ps, const unsigned* __restrict__ flags,
                                               u16* __restrict__ xb, u16* __restrict__ wb,
                                               float* __restrict__ bs, int do_x) {
    int blk = blockIdx.x, tid = threadIdx.x;
    int xblocks = do_x ? 2048 : 0;
    if (blk < xblocks) {                         // x: 4M elems
        long ei = ((long)blk * 256 + tid) * 8;
        *(short8*)(xb + ei) = cvt8any(ps.x, ei, flags[0]);
    } else if (blk < xblocks + 6 * 512) {        // weights: 1M elems each
        int r = (blk - xblocks) >> 9;
        const int fidx[6] = {1, 3, 5, 7, 9, 11};
        long ei = ((long)((blk - xblocks) & 511) * 256 + tid) * 8;
        *(short8*)(wb + (long)r * 1048576 + ei) = cvt8any(ps.W[r], ei, flags[fidx[r]]);
    } else {                                     // bias sums: bs[0]=z, [1]=r, [2]=h
        const int fb[3] = {2, 6, 10}, fc[3] = {4, 8, 12};
        for (int g = 0; g < 3; g++)
            for (int i = tid; i < 1024; i += 256) {
                float b = flags[fb[g]] ? bf2f(((const u16*)ps.b[2 * g])[i])
                                       : ((const float*)ps.b[2 * g])[i];
                float c = flags[fc[g]] ? bf2f(((const u16*)ps.b[2 * g + 1])[i])
                                       : ((const float*)ps.b[2 * g + 1])[i];
                bs[g * 1024 + i] = b + c;
            }
    }
}

// ---- persistent GRU: 64 blocks x 1024 thr, M=32 tiles, batched coh loads ----
// Block blk owns ALL 32 batches x 16 cols [blk*16, +16). Per step:
//   wait(h) -> A: w0-7 r-chains (hUr), w8-15 z-chains (hUz)  [both pre-arrive]
//   reduce r -> publish rh -> arrive ; gap: w8-15 xWh(t)
//   wait(rh) -> B: w0-7 rhUh -> combine z/hh/h' -> publish h -> arrive
//   gap: w0-7 xWr(t+1), w8-15 xWz(t+1)   (accumulators carried into next A)
__global__ __launch_bounds__(1024, 4) void gru_rec(
    const void* __restrict__ xbase, int xmode,   // 1: xbase bf16-staged; 0: raw x
    const u16* __restrict__ wb, const float* __restrict__ bs,
    u64* __restrict__ h64, u64* __restrict__ rh64,
    const unsigned* __restrict__ flags,
    unsigned* __restrict__ fl, void* __restrict__ out)
{
    const int tid  = threadIdx.x;
    const int lane = tid & 63, wave = tid >> 6;      // wave 0..15
    const int quad = lane >> 4, ln = lane & 15;
    const int blk  = blockIdx.x;

    const unsigned xisbf = xmode ? 1u : flags[0];
    const unsigned outbf = flags[0];
    const int C0 = blk * 16;

    const u16* Wz = wb;                  const u16* Uz = wb + 1048576;
    const u16* Wr = wb + 2 * 1048576;    const u16* Ur = wb + 3 * 1048576;
    const u16* Wh = wb + 4 * 1048576;    const u16* Uh = wb + 5 * 1048576;

    const int wk = wave & 7;             // K-slice index within role group
    const int ks = wk * 128;             // K-slice start
    const bool rgrp = (wave < 8);        // waves 0-7: r/rhUh side; 8-15: z/xWh side

    // coherent-load bases (u64 units): row ln (rt2=0) / row 16+ln (rt2=1)
    const u64* hb0 = h64 + ln * 256 + wk * 32 + quad * 2;
    const u64* hb1 = hb0 + 4096;
    const u64* rb0 = rh64 + ln * 256 + wk * 32 + quad * 2;
    const u64* rb1 = rb0 + 4096;

    // weight fragment base (B-operand: row = out-col C0+ln)
    const u16* UwA = (rgrp ? Ur : Uz) + (C0 + ln) * 1024 + ks + quad * 8;
    const u16* UhB = Uh + (C0 + ln) * 1024 + ks + quad * 8;

    const float bias_z = bs[C0 + ln];
    const float bias_r = bs[1024 + C0 + ln];
    const float bias_h = bs[2048 + C0 + ln];

    __shared__ float sA[8][2][4][64];    // r-partials (A) / rhUh-partials (B)
    __shared__ float sZ[8][2][4][64];    // z-partials (xWz + hUz)
    __shared__ float sXh[8][2][4][64];   // xWh partials
    __shared__ float ht[2][4][64];       // h fp32 tile (block-private)
    __shared__ u16   tT[32][20];         // transpose staging for u64 packing

    if (wave == 0) {
#pragma unroll
        for (int r = 0; r < 4; r++) { ht[0][r][lane] = 0.f; ht[1][r][lane] = 0.f; }
    }
    __syncthreads();

    // x-chain: acc[rt2] += x(rows rt2*16+ln)@W^T over this wave's K-slice
    auto xchain = [&](const u16* Wm, int t, f32x4* acc) {
        const long b0 = (long)ln * 131072 + (long)t * 1024 + ks + quad * 8;
        const long b1 = b0 + 16 * 131072;
        const u16* wp = Wm + (C0 + ln) * 1024 + ks + quad * 8;
#pragma unroll
        for (int i = 0; i < 4; i++) {
            short8 wf = *(const short8*)(wp + i * 32);
            acc[0] = __builtin_amdgcn_mfma_f32_16x16x32_bf16(
                cvt8any(xbase, b0 + i * 32, xisbf), wf, acc[0], 0, 0, 0);
            acc[1] = __builtin_amdgcn_mfma_f32_16x16x32_bf16(
                cvt8any(xbase, b1 + i * 32, xisbf), wf, acc[1], 0, 0, 0);
        }
    };

    const int w2 = wave;                             // reduce waves 0,1 -> rt2
    const int prow0 = (lane >> 2);                   // packer row within tile-half
    const int pseg = lane & 3;

    // ---- prelude: x-projections for t=0 ----
    f32x4 accR[2] = {(f32x4){0,0,0,0}, (f32x4){0,0,0,0}};   // waves 0-7: xWr+hUr
    f32x4 accZ[2] = {(f32x4){0,0,0,0}, (f32x4){0,0,0,0}};   // waves 8-15: xWz+hUz
    if (rgrp) xchain(Wr, 0, accR); else xchain(Wz, 0, accZ);

    for (int t = 0; t < 128; t++) {
        if (t > 0) gbar_wait(fl, 2 * t - 1);         // h_{t-1} published
        { // ---- window A: hUr (w0-7) / hUz (w8-15), batched coherent loads ----
            short8 wf[4];
#pragma unroll
            for (int i = 0; i < 4; i++) wf[i] = *(const short8*)(UwA + i * 32);
            short8 hf[8];
            ld8_coh(hb0, hb1, hf);
            f32x4* acc = rgrp ? accR : accZ;
#pragma unroll
            for (int i = 0; i < 4; i++) {
                acc[0] = __builtin_amdgcn_mfma_f32_16x16x32_bf16(hf[i], wf[i], acc[0], 0, 0, 0);
                acc[1] = __builtin_amdgcn_mfma_f32_16x16x32_bf16(hf[4 + i], wf[i], acc[1], 0, 0, 0);
            }
            if (rgrp) {
#pragma unroll
                for (int j = 0; j < 2; j++)
#pragma unroll
                    for (int r = 0; r < 4; r++) sA[wk][j][r][lane] = accR[j][r];
            } else {
#pragma unroll
                for (int j = 0; j < 2; j++)
#pragma unroll
                    for (int r = 0; r < 4; r++) sZ[wk][j][r][lane] = accZ[j][r];
            }
        }
        __syncthreads();
        if (wave < 2) {          // r-reduce (wave=rt2): rh = sigm(r)*h -> publish
#pragma unroll
            for (int r = 0; r < 4; r++) {
                float s = bias_r;
#pragma unroll
                for (int w = 0; w < 8; w++) s += sA[w][w2][r][lane];
                float rv = sigm(s);
                tT[w2 * 16 + quad * 4 + r][ln] = f2bf(rv * ht[w2][r][lane]);
            }
            int prow = w2 * 16 + prow0;
            u64 v = (u64)tT[prow][pseg * 4] | ((u64)tT[prow][pseg * 4 + 1] << 16)
                  | ((u64)tT[prow][pseg * 4 + 2] << 32) | ((u64)tT[prow][pseg * 4 + 3] << 48);
            __hip_atomic_store(&rh64[prow * 256 + blk * 4 + pseg], v,
                               __ATOMIC_RELAXED, __HIP_MEMORY_SCOPE_AGENT);
        }
        gbar_arrive(fl, 2 * t, blk);
        // ---- gap: w8-15 compute xWh(t) (pure x, race-free) ----
        if (!rgrp) {
            f32x4 accXh[2] = {(f32x4){0,0,0,0}, (f32x4){0,0,0,0}};
            xchain(Wh, t, accXh);
#pragma unroll
            for (int j = 0; j < 2; j++)
#pragma unroll
                for (int r = 0; r < 4; r++) sXh[wk][j][r][lane] = accXh[j][r];
        }
        gbar_wait(fl, 2 * t);                        // rh published
        if (rgrp) { // ---- window B: rhUh, batched coherent loads ----
            short8 wf[4];
#pragma unroll
            for (int i = 0; i < 4; i++) wf[i] = *(const short8*)(UhB + i * 32);
            short8 rf[8];
            ld8_coh(rb0, rb1, rf);
            f32x4 accB[2] = {(f32x4){0,0,0,0}, (f32x4){0,0,0,0}};
#pragma unroll
            for (int i = 0; i < 4; i++) {
                accB[0] = __builtin_amdgcn_mfma_f32_16x16x32_bf16(rf[i], wf[i], accB[0], 0, 0, 0);
                accB[1] = __builtin_amdgcn_mfma_f32_16x16x32_bf16(rf[4 + i], wf[i], accB[1], 0, 0, 0);
            }
#pragma unroll
            for (int j = 0; j < 2; j++)
#pragma unroll
                for (int r = 0; r < 4; r++) sA[wk][j][r][lane] = accB[j][r];
        }
        __syncthreads();
        if (wave < 2) {          // combine: h' = (1-z)h + z*sigm(.), publish h
#pragma unroll
            for (int r = 0; r < 4; r++) {
                float sz = bias_z, sh = bias_h;
#pragma unroll
                for (int w = 0; w < 8; w++) {
                    sz += sZ[w][w2][r][lane];
                    sh += sA[w][w2][r][lane] + sXh[w][w2][r][lane];
                }
                float z  = sigm(sz);
                float hh = sigm(sh);
                float hv = ht[w2][r][lane];
                float hn = (1.0f - z) * hv + z * hh;
                ht[w2][r][lane] = hn;
                u16 hb = f2bf(hn);
                int row = w2 * 16 + quad * 4 + r;
                tT[row][ln] = hb;
                long oi = ((long)(t * 32) + row) * 1024 + C0 + ln;   // ys (T,B,D)
                if (outbf) ((u16*)out)[oi] = hb;
                else       ((float*)out)[oi] = hn;
            }
            int prow = w2 * 16 + prow0;
            u64 v = (u64)tT[prow][pseg * 4] | ((u64)tT[prow][pseg * 4 + 1] << 16)
                  | ((u64)tT[prow][pseg * 4 + 2] << 32) | ((u64)tT[prow][pseg * 4 + 3] << 48);
            __hip_atomic_store(&h64[prow * 256 + blk * 4 + pseg], v,
                               __ATOMIC_RELAXED, __HIP_MEMORY_SCOPE_AGENT);
        }
        if (t < 127) {
            gbar_arrive(fl, 2 * t + 1, blk);
            // ---- gap: x-projections for t+1 (accumulators carried into A) ----
            accR[0] = (f32x4){0,0,0,0}; accR[1] = (f32x4){0,0,0,0};
            accZ[0] = (f32x4){0,0,0,0}; accZ[1] = (f32x4){0,0,0,0};
            if (rgrp) xchain(Wr, t + 1, accR); else xchain(Wz, t + 1, accZ);
        }
    }
}

extern "C" void kernel_launch(void* const* d_in, const int* in_sizes, int n_in,
                              void* d_out, int out_size, void* d_ws, size_t ws_size,
                              hipStream_t stream)
{
    char* ws = (char*)d_ws;
    hipMemsetAsync(d_ws, 0, ZERO_BYTES, stream);   // epoch flags + dtypes + h64

    unsigned* fl    = (unsigned*)(ws + FLAGA_OFF);
    unsigned* flags = (unsigned*)(ws + FLG_OFF);
    u64*      h64   = (u64*)(ws + H64_OFF);
    u64*      rh64  = (u64*)(ws + RH64_OFF);
    float*    bs    = (float*)(ws + BS_OFF);
    u16*      xb    = (u16*)(ws + XB_OFF);

    Ptrs dp;
    for (int i = 0; i < 13; i++) dp.p[i] = d_in[i];
    detect_k<<<13, 256, 0, stream>>>(dp, flags);

    SPtrs sp;
    sp.x = d_in[0];
    sp.W[0] = d_in[1];  sp.W[1] = d_in[3];   // Wz, Uz
    sp.W[2] = d_in[5];  sp.W[3] = d_in[7];   // Wr, Ur
    sp.W[4] = d_in[9];  sp.W[5] = d_in[11];  // Wh, Uh
    sp.b[0] = d_in[2];  sp.b[1] = d_in[4];   // bz, cz
    sp.b[2] = d_in[6];  sp.b[3] = d_in[8];   // br, cr
    sp.b[4] = d_in[10]; sp.b[5] = d_in[12];  // bh, ch

    if (ws_size >= WS_FULL) {
        u16* wbuf = (u16*)(ws + WB_OFF);
        stage_k<<<2048 + 6 * 512 + 1, 256, 0, stream>>>(sp, flags, xb, wbuf, bs, 1);
        gru_rec<<<NBLK, 1024, 0, stream>>>(xb, 1, wbuf, bs, h64, rh64, flags, fl, d_out);
    } else {
        u16* wbuf = (u16*)(ws + XB_OFF);     // no x staging; weights at 1 MB
        stage_k<<<6 * 512 + 1, 256, 0, stream>>>(sp, flags, xb, wbuf, bs, 0);
        gru_rec<<<NBLK, 1024, 0, stream>>>(d_in[0], 0, wbuf, bs, h64, rh64, flags, fl, d_out);
    }
}

// Round 10
// 2264.626 us; speedup vs baseline: 1.1904x; 1.1904x over previous
//
#include <hip/hip_runtime.h>
#include <stdint.h>

// B=32, T=128, DIN=DOUT=1024. Input dtypes detected at runtime (bf16 vs fp32).
typedef unsigned short u16;
typedef unsigned long long u64;
typedef __attribute__((ext_vector_type(8))) short short8;   // 8 x bf16 MFMA operand
typedef __attribute__((ext_vector_type(4))) float f32x4;    // MFMA accumulator
typedef __attribute__((ext_vector_type(4))) int i32x4;

// ---- workspace layout (bytes) ----
#define CNT_OFF    0                          // 256 epoch counters x 64 B
#define FLAGQ_OFF  16384                      // 256 epoch flags x 64 B
#define FLG_OFF    32768                      // 13 dtype flags
#define H64_OFF    36864                      // h bf16 as u64[32][256]: 64 KB (zeroed)
#define ZERO_BYTES (H64_OFF + 65536)
#define RH64_OFF   ZERO_BYTES                 // r*h bf16 u64[32][256] (write-before-read)
#define BS_OFF     (RH64_OFF + 65536)         // bias sums fp32: 3*1024*4
#define XB_OFF     (1<<20)                    // x bf16: 8 MB
#define WB_OFF     (9<<20)                    // 6 weight mats bf16: 12 MB
#define WS_FULL    (21u<<20)

__device__ __forceinline__ float bf2f(u16 v) {
    unsigned u = ((unsigned)v) << 16;
    return __builtin_bit_cast(float, u);
}
__device__ __forceinline__ u16 f2bf(float f) {
    unsigned u = __builtin_bit_cast(unsigned, f);
    unsigned r = 0x7fffu + ((u >> 16) & 1u);   // RNE
    return (u16)((u + r) >> 16);
}
__device__ __forceinline__ float sigm(float x) { return 1.0f / (1.0f + __expf(-x)); }

__device__ __forceinline__ short8 cvt8f(const float* f) {
    short8 r;
#pragma unroll
    for (int j = 0; j < 8; j++) r[j] = (short)f2bf(f[j]);
    return r;
}
__device__ __forceinline__ short8 cvt8any(const void* src, long ei, unsigned isbf) {
    if (isbf) return *(const short8*)((const u16*)src + ei);
    return cvt8f((const float*)src + ei);
}

// ---- batched coherent loads: N x dwordx4 sc1 in flight, ONE waitcnt ----
// __hip_atomic_load emits the same global_load ... sc1 but LLVM serializes each
// behind its own vmcnt(0) (R6-8: 16 back-to-back L3 round trips per window).
// These asm blocks issue all loads then wait once. Correctness-proven in R9.
__device__ __forceinline__ void ld8_coh(const u64* b, short8* f) {
    i32x4 g0, g1, g2, g3, g4, g5, g6, g7;
    asm volatile(
        "global_load_dwordx4 %0, %[p], off sc1\n\t"
        "global_load_dwordx4 %1, %[p], off offset:64 sc1\n\t"
        "global_load_dwordx4 %2, %[p], off offset:128 sc1\n\t"
        "global_load_dwordx4 %3, %[p], off offset:192 sc1\n\t"
        "global_load_dwordx4 %4, %[p], off offset:256 sc1\n\t"
        "global_load_dwordx4 %5, %[p], off offset:320 sc1\n\t"
        "global_load_dwordx4 %6, %[p], off offset:384 sc1\n\t"
        "global_load_dwordx4 %7, %[p], off offset:448 sc1\n\t"
        "s_waitcnt vmcnt(0)"
        : "=&v"(g0), "=&v"(g1), "=&v"(g2), "=&v"(g3),
          "=&v"(g4), "=&v"(g5), "=&v"(g6), "=&v"(g7)
        : [p]"v"(b)
        : "memory");
    f[0] = __builtin_bit_cast(short8, g0); f[1] = __builtin_bit_cast(short8, g1);
    f[2] = __builtin_bit_cast(short8, g2); f[3] = __builtin_bit_cast(short8, g3);
    f[4] = __builtin_bit_cast(short8, g4); f[5] = __builtin_bit_cast(short8, g5);
    f[6] = __builtin_bit_cast(short8, g6); f[7] = __builtin_bit_cast(short8, g7);
}
__device__ __forceinline__ void ld4_coh(const u64* b, short8* f) {
    i32x4 g0, g1, g2, g3;
    asm volatile(
        "global_load_dwordx4 %0, %[p], off sc1\n\t"
        "global_load_dwordx4 %1, %[p], off offset:64 sc1\n\t"
        "global_load_dwordx4 %2, %[p], off offset:128 sc1\n\t"
        "global_load_dwordx4 %3, %[p], off offset:192 sc1\n\t"
        "s_waitcnt vmcnt(0)"
        : "=&v"(g0), "=&v"(g1), "=&v"(g2), "=&v"(g3)
        : [p]"v"(b)
        : "memory");
    f[0] = __builtin_bit_cast(short8, g0); f[1] = __builtin_bit_cast(short8, g1);
    f[2] = __builtin_bit_cast(short8, g2); f[3] = __builtin_bit_cast(short8, g3);
}

// ---- fence-free grid barrier (R6 champion, verbatim) ----
__device__ __forceinline__ void gbar(unsigned* cnts, unsigned* flgs, unsigned e,
                                     int blk, unsigned nb) {
    __syncthreads();                 // drains vmcnt: all sc1 stores are at L3
    if (threadIdx.x == 0) {
        unsigned* c = cnts + e * 16;
        unsigned* f = flgs + e * 16;
        __hip_atomic_fetch_add(c, 1u, __ATOMIC_RELAXED, __HIP_MEMORY_SCOPE_AGENT);
        if (blk == 0) {
            while (__hip_atomic_load(c, __ATOMIC_RELAXED, __HIP_MEMORY_SCOPE_AGENT) < nb)
                __builtin_amdgcn_s_sleep(1);
            __hip_atomic_store(f, 1u, __ATOMIC_RELAXED, __HIP_MEMORY_SCOPE_AGENT);
        } else {
            while (__hip_atomic_load(f, __ATOMIC_RELAXED, __HIP_MEMORY_SCOPE_AGENT) == 0)
                __builtin_amdgcn_s_sleep(2);
        }
    }
    __syncthreads();
}

struct Ptrs { const void* p[13]; };

// dtype detector (proven rounds 3-9).
__global__ __launch_bounds__(256) void detect_k(Ptrs ps, unsigned* flags) {
    const u16* a = (const u16*)ps.p[blockIdx.x];
    __shared__ int tot;
    if (threadIdx.x == 0) tot = 0;
    __syncthreads();
    int cnt = 0;
    for (int i = threadIdx.x; i < 1024; i += 256) {
        unsigned u = a[i];
        unsigned e = (u >> 7) & 0xFF;
        cnt += (e == 0 || (e >= 100 && e <= 140)) ? 1 : 0;
    }
    atomicAdd(&tot, cnt);
    __syncthreads();
    if (threadIdx.x == 0) flags[blockIdx.x] = (tot >= 920) ? 1u : 0u;
}

struct SPtrs { const void* x; const void* W[6]; const void* b[6]; };
// W order: Wz,Uz,Wr,Ur,Wh,Uh (flags 1,3,5,7,9,11); b pairs (bz,cz),(br,cr),(bh,ch).

__global__ __launch_bounds__(256) void stage_k(SPtrs ps, const unsigned* __restrict__ flags,
                                               u16* __restrict__ xb, u16* __restrict__ wb,
                                               float* __restrict__ bs, int do_x) {
    int blk = blockIdx.x, tid = threadIdx.x;
    int xblocks = do_x ? 2048 : 0;
    if (blk < xblocks) {                         // x: 4M elems
        long ei = ((long)blk * 256 + tid) * 8;
        *(short8*)(xb + ei) = cvt8any(ps.x, ei, flags[0]);
    } else if (blk < xblocks + 6 * 512) {        // weights: 1M elems each
        int r = (blk - xblocks) >> 9;
        const int fidx[6] = {1, 3, 5, 7, 9, 11};
        long ei = ((long)((blk - xblocks) & 511) * 256 + tid) * 8;
        *(short8*)(wb + (long)r * 1048576 + ei) = cvt8any(ps.W[r], ei, flags[fidx[r]]);
    } else {                                     // bias sums: bs[0]=z, [1]=r, [2]=h
        const int fb[3] = {2, 6, 10}, fc[3] = {4, 8, 12};
        for (int g = 0; g < 3; g++)
            for (int i = tid; i < 1024; i += 256) {
                float b = flags[fb[g]] ? bf2f(((const u16*)ps.b[2 * g])[i])
                                       : ((const float*)ps.b[2 * g])[i];
                float c = flags[fc[g]] ? bf2f(((const u16*)ps.b[2 * g + 1])[i])
                                       : ((const float*)ps.b[2 * g + 1])[i];
                bs[g * 1024 + i] = b + c;
            }
    }
}

// ---- persistent GRU (R6 structure + batched coherent loads) ----
// 128 blocks x 1024 thr (16 waves). Block (ct=blk>>1, rt=blk&1) owns rows
// R=[16rt,+16), cols C=[16ct,+16). h / r*h as u64[32][256] via sc1 only.
__global__ __launch_bounds__(1024, 4) void gru_rec(
    const void* __restrict__ xbase, int xmode,   // 1: xbase bf16-staged; 0: raw x
    const u16* __restrict__ wb, const float* __restrict__ bs,
    u64* __restrict__ h64, u64* __restrict__ rh64,
    const unsigned* __restrict__ flags,
    unsigned* __restrict__ cnts, unsigned* __restrict__ flgs,
    void* __restrict__ out)
{
    const int tid  = threadIdx.x;
    const int lane = tid & 63, wave = tid >> 6;      // wave 0..15
    const int quad = lane >> 4, ln = lane & 15;
    const int blk  = blockIdx.x;
    const unsigned NB = gridDim.x;

    const unsigned xisbf = xmode ? 1u : flags[0];
    const unsigned outbf = flags[0];

    const int ct = blk >> 1, rt = blk & 1;
    const int R = rt * 16, C0 = ct * 16;

    // Phase A role: gA = wave>>2 (0:hUr 1:xWr 2:hUz 3:xWz), kqA = wave&3.
    const int gA  = wave >> 2, kqA = wave & 3;
    const bool hwA = (gA == 0) || (gA == 2);
    const int kb0 = kqA * 256;
    const int wmapA[4] = {3, 2, 1, 0};               // -> Ur, Wr, Uz, Wz
    const u16* BwA = wb + (long)wmapA[gA] * 1048576 + (C0 + ln) * 1024 + kb0 + quad * 8;
    const u64* hAq = h64 + (R + ln) * 256 + (kb0 >> 2) + quad * 2;   // iter i: +64 B
    const long xAo = ((long)(R + ln) * 128) * 1024 + kb0 + quad * 8; // + t*1024

    // Phase B role: gB = wave>>3 (0:rh@Uh 1:x@Wh), keB = wave&7.
    const int gB  = wave >> 3, keB = wave & 7;
    const int kb1 = keB * 128;
    const u16* BwB = wb + (long)(gB ? 4 : 5) * 1048576 + (C0 + ln) * 1024 + kb1 + quad * 8;
    const u64* rhq = rh64 + (R + ln) * 256 + (kb1 >> 2) + quad * 2;  // iter i: +64 B
    const long xBo = ((long)(R + ln) * 128) * 1024 + kb1 + quad * 8; // + t*1024

    const float bias_z = bs[C0 + ln];
    const float bias_r = bs[1024 + C0 + ln];
    const float bias_h = bs[2048 + C0 + ln];

    __shared__ float sA[16][4][64];    // per-wave partials (conflict-free layout)
    __shared__ float zt[4][64];        // z tile
    __shared__ float ht[4][64];        // h fp32 tile (block-private)
    __shared__ u16   tT[16][20];       // transpose staging for u64 packing

    if (wave == 0)
#pragma unroll
        for (int r = 0; r < 4; r++) ht[r][lane] = 0.f;
    __syncthreads();

    const int prow = lane >> 2, pseg = lane & 3;     // packer geometry (wave 0)

    for (int t = 0; t < 128; t++) {
        { // ---- phase A: hU chains (batched coh loads) / xW chains (inline) ----
            f32x4 acc = (f32x4){0.f, 0.f, 0.f, 0.f};
            if (hwA) {
                short8 hf[8];
                ld8_coh(hAq, hf);                    // 8 x 16B, one waitcnt
#pragma unroll
                for (int i = 0; i < 8; i++)
                    acc = __builtin_amdgcn_mfma_f32_16x16x32_bf16(
                        hf[i], *(const short8*)(BwA + i * 32), acc, 0, 0, 0);
            } else {
                const long xo = xAo + (long)t * 1024;
#pragma unroll
                for (int i = 0; i < 8; i++)
                    acc = __builtin_amdgcn_mfma_f32_16x16x32_bf16(
                        cvt8any(xbase, xo + i * 32, xisbf),
                        *(const short8*)(BwA + i * 32), acc, 0, 0, 0);
            }
#pragma unroll
            for (int r = 0; r < 4; r++) sA[wave][r][lane] = acc[r];
        }
        __syncthreads();
        if (wave == 0) {        // r -> r*h, transpose via LDS, publish u64 sc1
#pragma unroll
            for (int r = 0; r < 4; r++) {
                float s = bias_r;
#pragma unroll
                for (int w = 0; w < 8; w++) s += sA[w][r][lane];
                float rv = sigm(s);
                tT[quad * 4 + r][ln] = f2bf(rv * ht[r][lane]);
            }
            u64 v = (u64)tT[prow][pseg * 4] | ((u64)tT[prow][pseg * 4 + 1] << 16)
                  | ((u64)tT[prow][pseg * 4 + 2] << 32) | ((u64)tT[prow][pseg * 4 + 3] << 48);
            __hip_atomic_store(&rh64[(R + prow) * 256 + ct * 4 + pseg], v,
                               __ATOMIC_RELAXED, __HIP_MEMORY_SCOPE_AGENT);
        } else if (wave == 1) { // z -> LDS
#pragma unroll
            for (int r = 0; r < 4; r++) {
                float s = bias_z;
#pragma unroll
                for (int w = 8; w < 16; w++) s += sA[w][r][lane];
                zt[r][lane] = sigm(s);
            }
        }
        gbar(cnts, flgs, 2 * t, blk, NB);
        { // ---- phase B: rh chains (batched coh loads) / xWh (inline) ----
            f32x4 acc = (f32x4){0.f, 0.f, 0.f, 0.f};
            if (gB == 0) {
                short8 rf[4];
                ld4_coh(rhq, rf);                    // 4 x 16B, one waitcnt
#pragma unroll
                for (int i = 0; i < 4; i++)
                    acc = __builtin_amdgcn_mfma_f32_16x16x32_bf16(
                        rf[i], *(const short8*)(BwB + i * 32), acc, 0, 0, 0);
            } else {
                const long xo = xBo + (long)t * 1024;
#pragma unroll
                for (int i = 0; i < 4; i++)
                    acc = __builtin_amdgcn_mfma_f32_16x16x32_bf16(
                        cvt8any(xbase, xo + i * 32, xisbf),
                        *(const short8*)(BwB + i * 32), acc, 0, 0, 0);
            }
#pragma unroll
            for (int r = 0; r < 4; r++) sA[wave][r][lane] = acc[r];
        }
        __syncthreads();
        if (wave == 0) {        // combine: h' = (1-z)h + z*sigm(.), publish h
#pragma unroll
            for (int r = 0; r < 4; r++) {
                float s = bias_h;
#pragma unroll
                for (int w = 0; w < 16; w++) s += sA[w][r][lane];
                float hh = sigm(s);
                float z  = zt[r][lane];
                float hv = ht[r][lane];
                float hn = (1.0f - z) * hv + z * hh;
                ht[r][lane] = hn;
                u16 hb = f2bf(hn);
                int row = quad * 4 + r;
                tT[row][ln] = hb;
                long oi = ((long)(t * 32) + R + row) * 1024 + C0 + ln;  // ys (T,B,D)
                if (outbf) ((u16*)out)[oi] = hb;
                else       ((float*)out)[oi] = hn;
            }
            u64 v = (u64)tT[prow][pseg * 4] | ((u64)tT[prow][pseg * 4 + 1] << 16)
                  | ((u64)tT[prow][pseg * 4 + 2] << 32) | ((u64)tT[prow][pseg * 4 + 3] << 48);
            __hip_atomic_store(&h64[(R + prow) * 256 + ct * 4 + pseg], v,
                               __ATOMIC_RELAXED, __HIP_MEMORY_SCOPE_AGENT);
        }
        if (t < 127) gbar(cnts, flgs, 2 * t + 1, blk, NB);
    }
}

extern "C" void kernel_launch(void* const* d_in, const int* in_sizes, int n_in,
                              void* d_out, int out_size, void* d_ws, size_t ws_size,
                              hipStream_t stream)
{
    char* ws = (char*)d_ws;
    hipMemsetAsync(d_ws, 0, ZERO_BYTES, stream);   // counters + flags + dtypes + h64

    unsigned* cnts  = (unsigned*)(ws + CNT_OFF);
    unsigned* flgs  = (unsigned*)(ws + FLAGQ_OFF);
    unsigned* flags = (unsigned*)(ws + FLG_OFF);
    u64*      h64   = (u64*)(ws + H64_OFF);
    u64*      rh64  = (u64*)(ws + RH64_OFF);
    float*    bs    = (float*)(ws + BS_OFF);
    u16*      xb    = (u16*)(ws + XB_OFF);

    Ptrs dp;
    for (int i = 0; i < 13; i++) dp.p[i] = d_in[i];
    detect_k<<<13, 256, 0, stream>>>(dp, flags);

    SPtrs sp;
    sp.x = d_in[0];
    sp.W[0] = d_in[1];  sp.W[1] = d_in[3];   // Wz, Uz
    sp.W[2] = d_in[5];  sp.W[3] = d_in[7];   // Wr, Ur
    sp.W[4] = d_in[9];  sp.W[5] = d_in[11];  // Wh, Uh
    sp.b[0] = d_in[2];  sp.b[1] = d_in[4];   // bz, cz
    sp.b[2] = d_in[6];  sp.b[3] = d_in[8];   // br, cr
    sp.b[4] = d_in[10]; sp.b[5] = d_in[12];  // bh, ch

    if (ws_size >= WS_FULL) {
        u16* wbuf = (u16*)(ws + WB_OFF);
        stage_k<<<2048 + 6 * 512 + 1, 256, 0, stream>>>(sp, flags, xb, wbuf, bs, 1);
        gru_rec<<<128, 1024, 0, stream>>>(xb, 1, wbuf, bs, h64, rh64, flags, cnts, flgs, d_out);
    } else {
        u16* wbuf = (u16*)(ws + XB_OFF);     // no x staging; weights at 1 MB
        stage_k<<<6 * 512 + 1, 256, 0, stream>>>(sp, flags, xb, wbuf, bs, 0);
        gru_rec<<<128, 1024, 0, stream>>>(d_in[0], 0, wbuf, bs, h64, rh64, flags, cnts, flgs, d_out);
    }
}